// Round 11
// baseline (119.306 us; speedup 1.0000x reference)
//
#include <hip/hip_runtime.h>
#include <stdint.h>

#define BB 2
#define HH 16
#define LL 2048
#define DD 1024

typedef __bf16 b16x8 __attribute__((ext_vector_type(8)));
typedef __bf16 b16x4 __attribute__((ext_vector_type(4)));
typedef float f32x4 __attribute__((ext_vector_type(4)));
typedef int i32x4 __attribute__((ext_vector_type(4)));

__device__ __forceinline__ short f2bf(float f) {
  unsigned u = __builtin_bit_cast(unsigned, f);
  return (short)((u + 0x7fffu + ((u >> 16) & 1u)) >> 16);
}

// native bf16 convert
__device__ __forceinline__ short bfc(float f) {
  return __builtin_bit_cast(short, static_cast<__bf16>(f));
}

// packed f32x2 -> bf16x2 (no builtin on gfx950; HW-verified inline asm, T12)
__device__ __forceinline__ int cvtpk(float lo, float hi) {
  int r;
  asm("v_cvt_pk_bf16_f32 %0, %1, %2" : "=v"(r) : "v"(lo), "v"(hi));
  return r;
}

__device__ __forceinline__ void gl_lds16(const void* gp, void* lp) {
  __builtin_amdgcn_global_load_lds(
      (const __attribute__((address_space(1))) void*)gp,
      (__attribute__((address_space(3))) void*)lp, 16, 0, 0);
}

// ---------------- X f32 -> bf16 ----------------
__global__ __launch_bounds__(256) void xcvt(const float* __restrict__ X,
                                            short* __restrict__ Xb) {
  int i = blockIdx.x * 256 + threadIdx.x;
  float4 v = ((const float4*)X)[i];
  short4 o;
  o.x = f2bf(v.x); o.y = f2bf(v.y); o.z = f2bf(v.z); o.w = f2bf(v.w);
  ((short4*)Xb)[i] = o;
}

// ---------------- W[k][n] f32 -> Wt[n][k] bf16 (4 mats via blockIdx.z) ------
__global__ __launch_bounds__(256) void wtrans(const float* __restrict__ W0,
                                              const float* __restrict__ W1,
                                              const float* __restrict__ W2,
                                              const float* __restrict__ W3,
                                              short* __restrict__ Wt) {
  __shared__ float t[32][33];
  const float* W = blockIdx.z == 0 ? W0 : blockIdx.z == 1 ? W1
                 : blockIdx.z == 2 ? W2 : W3;
  short* dst = Wt + (size_t)blockIdx.z * DD * DD;
  int tx = threadIdx.x & 31, ty0 = threadIdx.x >> 5;
  int nb = blockIdx.x * 32, kb = blockIdx.y * 32;
#pragma unroll
  for (int i = 0; i < 4; ++i)
    t[ty0 + i * 8][tx] = W[(size_t)(kb + ty0 + i * 8) * DD + nb + tx];
  __syncthreads();
#pragma unroll
  for (int i = 0; i < 4; ++i)
    dst[(size_t)(nb + ty0 + i * 8) * DD + kb + tx] = f2bf(t[tx][ty0 + i * 8]);
}

// ---------------- fused QKV GEMM: [4096,1024] @ Wt -> Q,K,Vt ---------------
__global__ __launch_bounds__(256) void qkv_gemm(const short* __restrict__ Xb,
                                                const short* __restrict__ Wall,
                                                const float* __restrict__ bQ,
                                                const float* __restrict__ bK,
                                                const float* __restrict__ bV,
                                                short* __restrict__ Qo,
                                                short* __restrict__ Ko,
                                                short* __restrict__ Vto) {
  __shared__ __align__(16) short As[128 * 32];
  __shared__ __align__(16) short Bs[128 * 32];

  const int tid = threadIdx.x;
  const int lane = tid & 63;
  const int wid = tid >> 6;
  const int m0 = blockIdx.y * 128;
  const int ng = blockIdx.x * 128;
  const int sel = ng >> 10;
  const int n0 = ng & 1023;
  const short* W = Wall + (size_t)sel * DD * DD;

  const int wrow = wid >> 1, wcol = wid & 1;
  const int lrow = lane & 15;
  const int lk8 = (lane >> 4) * 8;
  const int srow = lane >> 2;
  const int scol = (lane & 3) * 8;

  f32x4 z4 = {0.f, 0.f, 0.f, 0.f};
  f32x4 acc[4][4];
#pragma unroll
  for (int i = 0; i < 4; ++i)
#pragma unroll
    for (int j = 0; j < 4; ++j) acc[i][j] = z4;

  for (int kt = 0; kt < DD; kt += 32) {
#pragma unroll
    for (int i = 0; i < 2; ++i) {
      int c = wid * 2 + i;
      gl_lds16(Xb + (size_t)(m0 + c * 16 + srow) * DD + kt + scol, As + c * 512);
      gl_lds16(W + (size_t)(n0 + c * 16 + srow) * DD + kt + scol, Bs + c * 512);
    }
    __syncthreads();
    b16x8 a[4], b[4];
#pragma unroll
    for (int i = 0; i < 4; ++i)
      a[i] = *(const b16x8*)(As + (wrow * 64 + i * 16 + lrow) * 32 + lk8);
#pragma unroll
    for (int j = 0; j < 4; ++j)
      b[j] = *(const b16x8*)(Bs + (wcol * 64 + j * 16 + lrow) * 32 + lk8);
#pragma unroll
    for (int i = 0; i < 4; ++i)
#pragma unroll
      for (int j = 0; j < 4; ++j)
        acc[i][j] = __builtin_amdgcn_mfma_f32_16x16x32_bf16(a[i], b[j], acc[i][j], 0, 0, 0);
    __syncthreads();
  }

  const float* bias = sel == 0 ? bQ : sel == 1 ? bK : bV;
  float bv[4];
#pragma unroll
  for (int j = 0; j < 4; ++j) bv[j] = bias[n0 + wcol * 64 + j * 16 + lrow];

  const int rbase = (lane >> 4) * 4;
  if (sel == 2) {
    // V: write transposed (B,H,DK,L) with keys PERMUTED within each 64-tile:
    // addr(key)= (kf>>1)*32 + hi*8 + (kf&1)*4 + t  (kf=key>>4, hi=(key>>2)&3,
    // t=key&3), so the attention PV fragment = one contiguous 16B b128 read.
#pragma unroll
    for (int i = 0; i < 4; ++i) {
      int gm = m0 + wrow * 64 + i * 16 + rbase;
      int bb = gm >> 11, lb = gm & 2047;
      int x = lb & 63;
      int kf = x >> 4;
      int lbp = (lb & ~63) | ((kf >> 1) << 5) | (((x >> 2) & 3) << 3) | ((kf & 1) << 2);
#pragma unroll
      for (int j = 0; j < 4; ++j) {
        int gn = n0 + wcol * 64 + j * 16 + lrow;
        int h = gn >> 6, dk = gn & 63;
        short4 pk;
        pk.x = bfc(acc[i][j][0] + bv[j]);
        pk.y = bfc(acc[i][j][1] + bv[j]);
        pk.z = bfc(acc[i][j][2] + bv[j]);
        pk.w = bfc(acc[i][j][3] + bv[j]);
        *(short4*)(Vto + ((size_t)((bb * HH + h) * 64 + dk)) * LL + lbp) = pk;
      }
    }
  } else {
    short* dst = sel == 0 ? Qo : Ko;
    // Q: fold 1/sqrt(64) AND log2(e) so softmax runs in exp2 domain.
    float sc = sel == 0 ? 0.18033688011112042f : 1.0f;
#pragma unroll
    for (int i = 0; i < 4; ++i) {
      int gm = m0 + wrow * 64 + i * 16 + rbase;
#pragma unroll
      for (int j = 0; j < 4; ++j) {
        int gn = n0 + wcol * 64 + j * 16 + lrow;
        int h = gn >> 6, dk = gn & 63;
#pragma unroll
        for (int r = 0; r < 4; ++r) {
          int m = gm + r;
          int bb = m >> 11, lq = m & 2047;
          dst[((size_t)(bb * HH + h) * LL + lq) * 64 + dk] =
              bfc((acc[i][j][r] + bv[j]) * sc);
        }
      }
    }
  }
}

// ---------------- flash attention (swapped-operand, 16 q-rows/wave) -------
// grid (32, 32): 64 q-rows/block, 4 waves x 16 rows -> 4096 waves = 4/SIMD
// (double the TLP of the 32q/wave version; both pipes were <45% busy).
// K/V LDS double-buffered (32KB -> 4 blocks/CU), gl_lds prefetch 1 ahead,
// vmcnt(0)+raw s_barrier per tile (TLP hides the drain). V keys pre-permuted
// in memory -> PV fragment = conflict-free b128. S^T = mfma(K,Q) keeps P
// in-register; packing via v_cvt_pk_bf16_f32; LDS offsets hoisted.
__global__ __launch_bounds__(256, 4) void attn(const short* __restrict__ Qg,
                                               const short* __restrict__ Kg,
                                               const short* __restrict__ Vt,
                                               short* __restrict__ Og) {
  __shared__ __align__(16) short Ks[2][64 * 64];  // [key][d], swizzled rows
  __shared__ __align__(16) short Vs[2][64 * 64];  // [d][perm-key], swizzled

  const int tid = threadIdx.x;
  const int lane = tid & 63;
  const int wid = tid >> 6;

  // bijective XCD-chunked swizzle: 1024 blocks -> 128 contiguous per XCD
  // = 4 bh values -> KV set 2MB fits the 4MB per-XCD L2.
  const int orig = blockIdx.x + 32 * blockIdx.y;
  const int nid = (orig & 7) * 128 + (orig >> 3);
  const int bh = nid >> 5;
  const int q0 = (nid & 31) * 64 + wid * 16;  // this wave's 16 q-rows

  const short* Qb = Qg + (size_t)bh * LL * 64;
  const short* Kb = Kg + (size_t)bh * LL * 64;
  const short* Vb = Vt + (size_t)bh * 64 * LL;

  const int lrow = lane & 15;
  const int hi = lane >> 4;     // 0..3
  const int hi8 = hi * 8;       // shorts
  const int hi16b = hi * 16;    // bytes
  const int r8 = lane >> 3;     // staging row within 8-row chunk
  const int c8 = lane & 7;
  const int swz8 = (c8 ^ r8) * 8;  // pre-swizzled global source offset (elems)

  // Q fragment: B-operand of swapped QK (col=q=lrow, k=hi*8+j)
  b16x8 qf[2];
#pragma unroll
  for (int ks = 0; ks < 2; ++ks)
    qf[ks] = *(const b16x8*)(Qb + (size_t)(q0 + lrow) * 64 + ks * 32 + hi8);

  f32x4 z4 = {0.f, 0.f, 0.f, 0.f};
  f32x4 accO[4];      // accO[db]: O^T[d=db*16+hi*4+r][q=lrow]
  float m_i = -1e30f, l_i = 0.f;  // l_i LANE-PARTIAL across hi
#pragma unroll
  for (int d = 0; d < 4; ++d) accO[d] = z4;

  // hoisted LDS read byte-offsets (identical table for K and V reads)
  int offs[4][2];
#pragma unroll
  for (int a = 0; a < 4; ++a) {
    int row = a * 16 + lrow;
    int sw = (row & 7) << 4;
#pragma unroll
    for (int ks = 0; ks < 2; ++ks)
      offs[a][ks] = row * 128 + ((ks * 64 + hi16b) ^ sw);
  }

#define STAGE(KT, BUF)                                                        \
  {                                                                           \
    _Pragma("unroll") for (int i = 0; i < 2; ++i) {                           \
      int c = wid * 2 + i;                                                    \
      gl_lds16(Kb + (size_t)((KT) * 64 + c * 8 + r8) * 64 + swz8,             \
               &Ks[BUF][c * 512]);                                            \
      gl_lds16(Vb + (size_t)(c * 8 + r8) * LL + (KT) * 64 + swz8,             \
               &Vs[BUF][c * 512]);                                            \
    }                                                                         \
  }

  // prologue
  STAGE(0, 0);
  asm volatile("s_waitcnt vmcnt(0)" ::: "memory");
  __builtin_amdgcn_s_barrier();

#define TILE(KT, BUF)                                                         \
  {                                                                           \
    if ((KT) + 1 < 32) STAGE((KT) + 1, (BUF) ^ 1);                            \
    const char* ksb = (const char*)&Ks[BUF][0];                               \
    const char* vsb = (const char*)&Vs[BUF][0];                               \
    /* S^T = mfma(K, Q): sacc[kf][r] = S[key=kf*16+hi*4+r][q=lrow] */         \
    f32x4 sacc[4];                                                            \
    _Pragma("unroll") for (int kf = 0; kf < 4; ++kf) sacc[kf] = z4;           \
    __builtin_amdgcn_s_setprio(1);                                            \
    _Pragma("unroll") for (int kf = 0; kf < 4; ++kf)                          \
        _Pragma("unroll") for (int ks = 0; ks < 2; ++ks) {                    \
      b16x8 kfr = *(const b16x8*)(ksb + offs[kf][ks]);                        \
      sacc[kf] = __builtin_amdgcn_mfma_f32_16x16x32_bf16(kfr, qf[ks],         \
                                                         sacc[kf], 0, 0, 0);  \
    }                                                                         \
    __builtin_amdgcn_s_setprio(0);                                            \
    /* defer-max online softmax (keys lane-local) */                          \
    float mx = fmaxf(fmaxf(sacc[0][0], sacc[0][1]),                           \
                     fmaxf(sacc[0][2], sacc[0][3]));                          \
    _Pragma("unroll") for (int kf = 1; kf < 4; ++kf)                          \
        mx = fmaxf(mx, fmaxf(fmaxf(sacc[kf][0], sacc[kf][1]),                 \
                             fmaxf(sacc[kf][2], sacc[kf][3])));               \
    if (!__all(mx - m_i <= 8.0f)) {                                           \
      float t = fmaxf(mx, __shfl_xor(mx, 16));                                \
      t = fmaxf(t, __shfl_xor(t, 32));                                        \
      float mnew = fmaxf(m_i, t);                                             \
      float corr = __builtin_amdgcn_exp2f(m_i - mnew);                        \
      l_i *= corr;                                                            \
      m_i = mnew;                                                             \
      _Pragma("unroll") for (int d = 0; d < 4; ++d) accO[d] *= corr;          \
    }                                                                         \
    /* P = exp2(S - m) packed via v_cvt_pk_bf16_f32 into the PV B-frag */     \
    b16x8 pfr[2];                                                             \
    float ps = 0.f;                                                           \
    _Pragma("unroll") for (int c = 0; c < 2; ++c) {                           \
      float e0 = __builtin_amdgcn_exp2f(sacc[2 * c][0] - m_i);                \
      float e1 = __builtin_amdgcn_exp2f(sacc[2 * c][1] - m_i);                \
      float e2 = __builtin_amdgcn_exp2f(sacc[2 * c][2] - m_i);                \
      float e3 = __builtin_amdgcn_exp2f(sacc[2 * c][3] - m_i);                \
      float e4 = __builtin_amdgcn_exp2f(sacc[2 * c + 1][0] - m_i);            \
      float e5 = __builtin_amdgcn_exp2f(sacc[2 * c + 1][1] - m_i);            \
      float e6 = __builtin_amdgcn_exp2f(sacc[2 * c + 1][2] - m_i);            \
      float e7 = __builtin_amdgcn_exp2f(sacc[2 * c + 1][3] - m_i);            \
      ps += ((e0 + e1) + (e2 + e3)) + ((e4 + e5) + (e6 + e7));                \
      i32x4 pt;                                                               \
      pt[0] = cvtpk(e0, e1);                                                  \
      pt[1] = cvtpk(e2, e3);                                                  \
      pt[2] = cvtpk(e4, e5);                                                  \
      pt[3] = cvtpk(e6, e7);                                                  \
      pfr[c] = __builtin_bit_cast(b16x8, pt);                                 \
    }                                                                         \
    l_i += ps;                                                                \
    /* O^T += mfma(V, P); V read = conflict-free b128 (perm-key layout) */    \
    __builtin_amdgcn_s_setprio(1);                                            \
    _Pragma("unroll") for (int db = 0; db < 4; ++db) {                        \
      b16x8 v0 = *(const b16x8*)(vsb + offs[db][0]);                          \
      b16x8 v1 = *(const b16x8*)(vsb + offs[db][1]);                          \
      accO[db] = __builtin_amdgcn_mfma_f32_16x16x32_bf16(v0, pfr[0],          \
                                                         accO[db], 0, 0, 0);  \
      accO[db] = __builtin_amdgcn_mfma_f32_16x16x32_bf16(v1, pfr[1],          \
                                                         accO[db], 0, 0, 0);  \
    }                                                                         \
    __builtin_amdgcn_s_setprio(0);                                            \
    /* this wave's next-tile stage must be resident; barrier guards ring */   \
    asm volatile("s_waitcnt vmcnt(0)" ::: "memory");                          \
    __builtin_amdgcn_s_barrier();                                             \
  }

  for (int kt = 0; kt < 32; kt += 2) {
    TILE(kt, 0);
    TILE(kt + 1, 1);
  }
#undef TILE
#undef STAGE

  // epilogue: reduce lane-partial l across hi, O /= l, packed short4 stores
  const int bb = bh >> 4, h = bh & 15;
  float l = l_i;
  l += __shfl_xor(l, 16);
  l += __shfl_xor(l, 32);
  float rl = 1.0f / l;
  int q = q0 + lrow;
#pragma unroll
  for (int db = 0; db < 4; ++db) {
    short4 pk;
    pk.x = bfc(accO[db][0] * rl);
    pk.y = bfc(accO[db][1] * rl);
    pk.z = bfc(accO[db][2] * rl);
    pk.w = bfc(accO[db][3] * rl);
    *(short4*)(Og + (size_t)(bb * LL + q) * DD + h * 64 + db * 16 + hi * 4) = pk;
  }
}

// ---------------- output GEMM: attn[4096,1024] @ WOt + bO -> f32 ----------
__global__ __launch_bounds__(256) void out_gemm(const short* __restrict__ Ab,
                                                const short* __restrict__ Wt,
                                                const float* __restrict__ bO,
                                                float* __restrict__ Out) {
  __shared__ __align__(16) short As[128 * 32];
  __shared__ __align__(16) short Bs[128 * 32];

  const int tid = threadIdx.x;
  const int lane = tid & 63;
  const int wid = tid >> 6;
  const int m0 = blockIdx.y * 128;
  const int n0 = blockIdx.x * 128;

  const int wrow = wid >> 1, wcol = wid & 1;
  const int lrow = lane & 15;
  const int lk8 = (lane >> 4) * 8;
  const int srow = lane >> 2;
  const int scol = (lane & 3) * 8;

  f32x4 z4 = {0.f, 0.f, 0.f, 0.f};
  f32x4 acc[4][4];
#pragma unroll
  for (int i = 0; i < 4; ++i)
#pragma unroll
    for (int j = 0; j < 4; ++j) acc[i][j] = z4;

  for (int kt = 0; kt < DD; kt += 32) {
#pragma unroll
    for (int i = 0; i < 2; ++i) {
      int c = wid * 2 + i;
      gl_lds16(Ab + (size_t)(m0 + c * 16 + srow) * DD + kt + scol, As + c * 512);
      gl_lds16(Wt + (size_t)(n0 + c * 16 + srow) * DD + kt + scol, Bs + c * 512);
    }
    __syncthreads();
    b16x8 a[4], b[4];
#pragma unroll
    for (int i = 0; i < 4; ++i)
      a[i] = *(const b16x8*)(As + (wrow * 64 + i * 16 + lrow) * 32 + lk8);
#pragma unroll
    for (int j = 0; j < 4; ++j)
      b[j] = *(const b16x8*)(Bs + (wcol * 64 + j * 16 + lrow) * 32 + lk8);
#pragma unroll
    for (int i = 0; i < 4; ++i)
#pragma unroll
      for (int j = 0; j < 4; ++j)
        acc[i][j] = __builtin_amdgcn_mfma_f32_16x16x32_bf16(a[i], b[j], acc[i][j], 0, 0, 0);
    __syncthreads();
  }

  float bv[4];
#pragma unroll
  for (int j = 0; j < 4; ++j) bv[j] = bO[n0 + wcol * 64 + j * 16 + lrow];

  const int rbase = (lane >> 4) * 4;
#pragma unroll
  for (int i = 0; i < 4; ++i) {
    int gm = m0 + wrow * 64 + i * 16 + rbase;
#pragma unroll
    for (int j = 0; j < 4; ++j) {
      int gn = n0 + wcol * 64 + j * 16 + lrow;
#pragma unroll
      for (int r = 0; r < 4; ++r)
        Out[(size_t)(gm + r) * DD + gn] = acc[i][j][r] + bv[j];
    }
  }
}

extern "C" void kernel_launch(void* const* d_in, const int* in_sizes, int n_in,
                              void* d_out, int out_size, void* d_ws, size_t ws_size,
                              hipStream_t stream) {
  const float* X = (const float*)d_in[0];
  const float* WQ = (const float*)d_in[1];
  const float* bQ = (const float*)d_in[2];
  const float* WK = (const float*)d_in[3];
  const float* bK = (const float*)d_in[4];
  const float* WV = (const float*)d_in[5];
  const float* bV = (const float*)d_in[6];
  const float* WO = (const float*)d_in[7];
  const float* bO = (const float*)d_in[8];
  float* Out = (float*)d_out;

  // workspace layout (shorts): Xb 4M | Wt 4x1M | Q 4M | K 4M | Vt 4M | At 4M
  if (ws_size < (size_t)24 * 1024 * 1024 * 2) return;
  short* ws = (short*)d_ws;
  short* Xb = ws;
  short* Wt = Xb + (size_t)4096 * 1024;
  short* Qb = Wt + (size_t)4 * 1024 * 1024;
  short* Kb = Qb + (size_t)4096 * 1024;
  short* Vtb = Kb + (size_t)4096 * 1024;
  short* At = Vtb + (size_t)4096 * 1024;

  hipLaunchKernelGGL(xcvt, dim3(4096), dim3(256), 0, stream, X, Xb);
  hipLaunchKernelGGL(wtrans, dim3(32, 32, 4), dim3(256), 0, stream, WQ, WK, WV, WO, Wt);
  hipLaunchKernelGGL(qkv_gemm, dim3(24, 32), dim3(256), 0, stream, Xb, Wt, bQ, bK, bV,
                     Qb, Kb, Vtb);
  hipLaunchKernelGGL(attn, dim3(32, 32), dim3(256), 0, stream, Qb, Kb, Vtb, At);
  hipLaunchKernelGGL(out_gemm, dim3(8, 32), dim3(256), 0, stream, At,
                     Wt + (size_t)3 * 1024 * 1024, bO, Out);
}

// Round 12
// 111.807 us; speedup vs baseline: 1.0671x; 1.0671x over previous
//
#include <hip/hip_runtime.h>
#include <stdint.h>

#define BB 2
#define HH 16
#define LL 2048
#define DD 1024

typedef __bf16 b16x8 __attribute__((ext_vector_type(8)));
typedef float f32x4 __attribute__((ext_vector_type(4)));
typedef int i32x4 __attribute__((ext_vector_type(4)));

__device__ __forceinline__ short f2bf(float f) {
  unsigned u = __builtin_bit_cast(unsigned, f);
  return (short)((u + 0x7fffu + ((u >> 16) & 1u)) >> 16);
}

// native bf16 convert
__device__ __forceinline__ short bfc(float f) {
  return __builtin_bit_cast(short, static_cast<__bf16>(f));
}

// packed f32x2 -> bf16x2 (no builtin on gfx950; inline asm)
__device__ __forceinline__ int cvtpk(float lo, float hi) {
  int r;
  asm("v_cvt_pk_bf16_f32 %0, %1, %2" : "=v"(r) : "v"(lo), "v"(hi));
  return r;
}

__device__ __forceinline__ void gl_lds16(const void* gp, void* lp) {
  __builtin_amdgcn_global_load_lds(
      (const __attribute__((address_space(1))) void*)gp,
      (__attribute__((address_space(3))) void*)lp, 16, 0, 0);
}

// ---------------- X f32 -> bf16 ----------------
__global__ __launch_bounds__(256) void xcvt(const float* __restrict__ X,
                                            short* __restrict__ Xb) {
  int i = blockIdx.x * 256 + threadIdx.x;
  float4 v = ((const float4*)X)[i];
  short4 o;
  o.x = f2bf(v.x); o.y = f2bf(v.y); o.z = f2bf(v.z); o.w = f2bf(v.w);
  ((short4*)Xb)[i] = o;
}

// ---------------- W[k][n] f32 -> Wt[n][k] bf16 (4 mats via blockIdx.z) ------
__global__ __launch_bounds__(256) void wtrans(const float* __restrict__ W0,
                                              const float* __restrict__ W1,
                                              const float* __restrict__ W2,
                                              const float* __restrict__ W3,
                                              short* __restrict__ Wt) {
  __shared__ float t[32][33];
  const float* W = blockIdx.z == 0 ? W0 : blockIdx.z == 1 ? W1
                 : blockIdx.z == 2 ? W2 : W3;
  short* dst = Wt + (size_t)blockIdx.z * DD * DD;
  int tx = threadIdx.x & 31, ty0 = threadIdx.x >> 5;
  int nb = blockIdx.x * 32, kb = blockIdx.y * 32;
#pragma unroll
  for (int i = 0; i < 4; ++i)
    t[ty0 + i * 8][tx] = W[(size_t)(kb + ty0 + i * 8) * DD + nb + tx];
  __syncthreads();
#pragma unroll
  for (int i = 0; i < 4; ++i)
    dst[(size_t)(nb + ty0 + i * 8) * DD + kb + tx] = f2bf(t[tx][ty0 + i * 8]);
}

// ---------------- fused QKV GEMM: [4096,1024] @ Wt -> Q,K,Vt ---------------
// XCD-chunked swizzle: 768 = 8 x 96; each XCD owns 3 n-panels (L2-resident).
__global__ __launch_bounds__(256) void qkv_gemm(const short* __restrict__ Xb,
                                                const short* __restrict__ Wall,
                                                const float* __restrict__ bQ,
                                                const float* __restrict__ bK,
                                                const float* __restrict__ bV,
                                                short* __restrict__ Qo,
                                                short* __restrict__ Ko,
                                                short* __restrict__ Vto) {
  __shared__ __align__(16) short As[128 * 32];
  __shared__ __align__(16) short Bs[128 * 32];

  const int tid = threadIdx.x;
  const int lane = tid & 63;
  const int wid = tid >> 6;
  const int orig = blockIdx.x + 24 * blockIdx.y;
  const int nid = (orig & 7) * 96 + (orig >> 3);
  const int m0 = (nid & 31) * 128;
  const int ng = (nid >> 5) * 128;
  const int sel = ng >> 10;
  const int n0 = ng & 1023;
  const short* W = Wall + (size_t)sel * DD * DD;

  const int wrow = wid >> 1, wcol = wid & 1;
  const int lrow = lane & 15;
  const int lk8 = (lane >> 4) * 8;
  const int srow = lane >> 2;
  const int scol = (lane & 3) * 8;

  f32x4 z4 = {0.f, 0.f, 0.f, 0.f};
  f32x4 acc[4][4];
#pragma unroll
  for (int i = 0; i < 4; ++i)
#pragma unroll
    for (int j = 0; j < 4; ++j) acc[i][j] = z4;

  for (int kt = 0; kt < DD; kt += 32) {
#pragma unroll
    for (int i = 0; i < 2; ++i) {
      int c = wid * 2 + i;
      gl_lds16(Xb + (size_t)(m0 + c * 16 + srow) * DD + kt + scol, As + c * 512);
      gl_lds16(W + (size_t)(n0 + c * 16 + srow) * DD + kt + scol, Bs + c * 512);
    }
    __syncthreads();
    b16x8 a[4], b[4];
#pragma unroll
    for (int i = 0; i < 4; ++i)
      a[i] = *(const b16x8*)(As + (wrow * 64 + i * 16 + lrow) * 32 + lk8);
#pragma unroll
    for (int j = 0; j < 4; ++j)
      b[j] = *(const b16x8*)(Bs + (wcol * 64 + j * 16 + lrow) * 32 + lk8);
#pragma unroll
    for (int i = 0; i < 4; ++i)
#pragma unroll
      for (int j = 0; j < 4; ++j)
        acc[i][j] = __builtin_amdgcn_mfma_f32_16x16x32_bf16(a[i], b[j], acc[i][j], 0, 0, 0);
    __syncthreads();
  }

  const float* bias = sel == 0 ? bQ : sel == 1 ? bK : bV;
  float bv[4];
#pragma unroll
  for (int j = 0; j < 4; ++j) bv[j] = bias[n0 + wcol * 64 + j * 16 + lrow];

  const int rbase = (lane >> 4) * 4;
  if (sel == 2) {
    // V: write transposed (B,H,DK,L) with keys PERMUTED within each 64-tile:
    // addr(key)= (kf>>1)*32 + hi*8 + (kf&1)*4 + t  (kf=key>>4, hi=(key>>2)&3,
    // t=key&3), so the attention PV fragment = one contiguous 16B b128 read.
#pragma unroll
    for (int i = 0; i < 4; ++i) {
      int gm = m0 + wrow * 64 + i * 16 + rbase;
      int bb = gm >> 11, lb = gm & 2047;
      int x = lb & 63;
      int kf = x >> 4;
      int lbp = (lb & ~63) | ((kf >> 1) << 5) | (((x >> 2) & 3) << 3) | ((kf & 1) << 2);
#pragma unroll
      for (int j = 0; j < 4; ++j) {
        int gn = n0 + wcol * 64 + j * 16 + lrow;
        int h = gn >> 6, dk = gn & 63;
        short4 pk;
        pk.x = bfc(acc[i][j][0] + bv[j]);
        pk.y = bfc(acc[i][j][1] + bv[j]);
        pk.z = bfc(acc[i][j][2] + bv[j]);
        pk.w = bfc(acc[i][j][3] + bv[j]);
        *(short4*)(Vto + ((size_t)((bb * HH + h) * 64 + dk)) * LL + lbp) = pk;
      }
    }
  } else {
    short* dst = sel == 0 ? Qo : Ko;
    // Q: fold 1/sqrt(64) AND log2(e) so softmax runs in exp2 domain.
    float sc = sel == 0 ? 0.18033688011112042f : 1.0f;
#pragma unroll
    for (int i = 0; i < 4; ++i) {
      int gm = m0 + wrow * 64 + i * 16 + rbase;
#pragma unroll
      for (int j = 0; j < 4; ++j) {
        int gn = n0 + wcol * 64 + j * 16 + lrow;
        int h = gn >> 6, dk = gn & 63;
#pragma unroll
        for (int r = 0; r < 4; ++r) {
          int m = gm + r;
          int bb = m >> 11, lq = m & 2047;
          dst[((size_t)(bb * HH + h) * LL + lq) * 64 + dk] =
              bfc((acc[i][j][r] + bv[j]) * sc);
        }
      }
    }
  }
}

// ---------------- flash attention (swapped-operand, 2-tile pipeline) ------
// grid (16, 32): 128 q-rows/block, 4 waves x 32 rows, XCD-chunked swizzle.
// 4-slot LDS ring (64KB): tiles processed in PAIRS with manual skew
// QK(t)->SM(t)->QK(t+1)->PV(t)->SM(t+1)->PV(t+1) and ONE vmcnt(0)+barrier
// per 2 tiles (16 barriers vs 32). QK(t+1)'s MFMA/LDS work overlaps SM(t)'s
// VALU work. V keys pre-permuted in memory -> PV read = conflict-free b128.
// S^T = mfma(K,Q) keeps P in-register; cvt_pk packing; hoisted LDS offsets.
__global__ __launch_bounds__(256, 2) void attn(const short* __restrict__ Qg,
                                               const short* __restrict__ Kg,
                                               const short* __restrict__ Vt,
                                               short* __restrict__ Og) {
  __shared__ __align__(16) short Ks[4][64 * 64];  // [key][d], swizzled rows
  __shared__ __align__(16) short Vs[4][64 * 64];  // [d][perm-key], swizzled

  const int tid = threadIdx.x;
  const int lane = tid & 63;
  const int wid = tid >> 6;

  // bijective XCD-chunked swizzle: 512 = 8 x 64 -> 4 bh per XCD (2MB KV/L2)
  const int orig = blockIdx.x + 16 * blockIdx.y;
  const int nid = (orig & 7) * 64 + (orig >> 3);
  const int bh = nid >> 4;
  const int q0 = (nid & 15) * 128 + wid * 32;

  const short* Qb = Qg + (size_t)bh * LL * 64;
  const short* Kb = Kg + (size_t)bh * LL * 64;
  const short* Vb = Vt + (size_t)bh * 64 * LL;

  const int lrow = lane & 15;
  const int hi = lane >> 4;     // 0..3
  const int hi8 = hi * 8;       // shorts
  const int hi16b = hi * 16;    // bytes
  const int r8 = lane >> 3;     // staging row within 8-row chunk
  const int c8 = lane & 7;
  const int swz8 = (c8 ^ r8) * 8;  // pre-swizzled global source offset (elems)

  // Q fragment: B-operand of swapped QK (col=q=lrow, k=hi*8+j)
  b16x8 qf[2][2];
#pragma unroll
  for (int f = 0; f < 2; ++f)
#pragma unroll
    for (int ks = 0; ks < 2; ++ks)
      qf[f][ks] = *(const b16x8*)(Qb + (size_t)(q0 + f * 16 + lrow) * 64 + ks * 32 + hi8);

  f32x4 z4 = {0.f, 0.f, 0.f, 0.f};
  f32x4 accO[2][4];            // accO[f][db]: O^T[d=db*16+hi*4+r][q=f*16+lrow]
  float m_i[2], l_i[2];        // per-q scalars; l_i LANE-PARTIAL across hi
#pragma unroll
  for (int f = 0; f < 2; ++f) {
#pragma unroll
    for (int d = 0; d < 4; ++d) accO[f][d] = z4;
    m_i[f] = -1e30f; l_i[f] = 0.f;
  }

  // hoisted LDS read byte-offsets (identical table for K and V reads)
  int offs[4][2];
#pragma unroll
  for (int a = 0; a < 4; ++a) {
    int row = a * 16 + lrow;
    int sw = (row & 7) << 4;
#pragma unroll
    for (int ks = 0; ks < 2; ++ks)
      offs[a][ks] = row * 128 + ((ks * 64 + hi16b) ^ sw);
  }

#define STAGE(KT, SL)                                                         \
  {                                                                           \
    _Pragma("unroll") for (int i = 0; i < 2; ++i) {                           \
      int c = wid * 2 + i;                                                    \
      gl_lds16(Kb + (size_t)((KT) * 64 + c * 8 + r8) * 64 + swz8,             \
               &Ks[SL][c * 512]);                                             \
      gl_lds16(Vb + (size_t)(c * 8 + r8) * LL + (KT) * 64 + swz8,             \
               &Vs[SL][c * 512]);                                             \
    }                                                                         \
  }

#define QKPH(SL, SACC)                                                       \
  {                                                                          \
    const char* ksb = (const char*)&Ks[SL][0];                               \
    _Pragma("unroll") for (int f = 0; f < 2; ++f)                            \
        _Pragma("unroll") for (int kf = 0; kf < 4; ++kf) SACC[f][kf] = z4;   \
    __builtin_amdgcn_s_setprio(1);                                           \
    _Pragma("unroll") for (int kf = 0; kf < 4; ++kf)                         \
        _Pragma("unroll") for (int ks = 0; ks < 2; ++ks) {                   \
      b16x8 kfr = *(const b16x8*)(ksb + offs[kf][ks]);                       \
      _Pragma("unroll") for (int f = 0; f < 2; ++f)                          \
          SACC[f][kf] = __builtin_amdgcn_mfma_f32_16x16x32_bf16(             \
              kfr, qf[f][ks], SACC[f][kf], 0, 0, 0);                         \
    }                                                                        \
    __builtin_amdgcn_s_setprio(0);                                           \
  }

#define SMPH(SACC, PFR)                                                      \
  {                                                                          \
    float lm[2];                                                             \
    _Pragma("unroll") for (int f = 0; f < 2; ++f) {                          \
      float mx = fmaxf(fmaxf(SACC[f][0][0], SACC[f][0][1]),                  \
                       fmaxf(SACC[f][0][2], SACC[f][0][3]));                 \
      _Pragma("unroll") for (int kf = 1; kf < 4; ++kf)                       \
          mx = fmaxf(mx, fmaxf(fmaxf(SACC[f][kf][0], SACC[f][kf][1]),        \
                               fmaxf(SACC[f][kf][2], SACC[f][kf][3])));      \
      lm[f] = mx;                                                            \
    }                                                                        \
    float w = fmaxf(lm[0] - m_i[0], lm[1] - m_i[1]);                         \
    if (!__all(w <= 8.0f)) {                                                 \
      _Pragma("unroll") for (int f = 0; f < 2; ++f) {                        \
        float mx = lm[f];                                                    \
        mx = fmaxf(mx, __shfl_xor(mx, 16));                                  \
        mx = fmaxf(mx, __shfl_xor(mx, 32));                                  \
        float mnew = fmaxf(m_i[f], mx);                                      \
        float corr = __builtin_amdgcn_exp2f(m_i[f] - mnew);                  \
        l_i[f] *= corr;                                                      \
        m_i[f] = mnew;                                                       \
        _Pragma("unroll") for (int d = 0; d < 4; ++d) accO[f][d] *= corr;    \
      }                                                                      \
    }                                                                        \
    _Pragma("unroll") for (int f = 0; f < 2; ++f) {                          \
      float ps = 0.f;                                                        \
      _Pragma("unroll") for (int c = 0; c < 2; ++c) {                        \
        float e0 = __builtin_amdgcn_exp2f(SACC[f][2 * c][0] - m_i[f]);       \
        float e1 = __builtin_amdgcn_exp2f(SACC[f][2 * c][1] - m_i[f]);       \
        float e2 = __builtin_amdgcn_exp2f(SACC[f][2 * c][2] - m_i[f]);       \
        float e3 = __builtin_amdgcn_exp2f(SACC[f][2 * c][3] - m_i[f]);       \
        float e4 = __builtin_amdgcn_exp2f(SACC[f][2 * c + 1][0] - m_i[f]);   \
        float e5 = __builtin_amdgcn_exp2f(SACC[f][2 * c + 1][1] - m_i[f]);   \
        float e6 = __builtin_amdgcn_exp2f(SACC[f][2 * c + 1][2] - m_i[f]);   \
        float e7 = __builtin_amdgcn_exp2f(SACC[f][2 * c + 1][3] - m_i[f]);   \
        ps += ((e0 + e1) + (e2 + e3)) + ((e4 + e5) + (e6 + e7));             \
        i32x4 pt;                                                            \
        pt[0] = cvtpk(e0, e1);                                               \
        pt[1] = cvtpk(e2, e3);                                               \
        pt[2] = cvtpk(e4, e5);                                               \
        pt[3] = cvtpk(e6, e7);                                               \
        PFR[f][c] = __builtin_bit_cast(b16x8, pt);                           \
      }                                                                      \
      l_i[f] += ps;                                                          \
    }                                                                        \
  }

#define PVPH(SL, PFR)                                                        \
  {                                                                          \
    const char* vsb = (const char*)&Vs[SL][0];                               \
    __builtin_amdgcn_s_setprio(1);                                           \
    _Pragma("unroll") for (int db = 0; db < 4; ++db) {                       \
      b16x8 v0 = *(const b16x8*)(vsb + offs[db][0]);                         \
      b16x8 v1 = *(const b16x8*)(vsb + offs[db][1]);                         \
      _Pragma("unroll") for (int f = 0; f < 2; ++f) {                        \
        accO[f][db] = __builtin_amdgcn_mfma_f32_16x16x32_bf16(               \
            v0, PFR[f][0], accO[f][db], 0, 0, 0);                            \
        accO[f][db] = __builtin_amdgcn_mfma_f32_16x16x32_bf16(               \
            v1, PFR[f][1], accO[f][db], 0, 0, 0);                            \
      }                                                                      \
    }                                                                        \
    __builtin_amdgcn_s_setprio(0);                                           \
  }

  // one pair of tiles: read slots {B0,B1}, prefetch into the other pair
#define BODY(B0, B1, KT, PF)                                                 \
  {                                                                          \
    if (PF) { STAGE((KT) + 2, (B0) ^ 2); STAGE((KT) + 3, ((B0) ^ 2) + 1); }  \
    f32x4 sA[2][4], sB[2][4];                                                \
    b16x8 pA[2][2], pB[2][2];                                                \
    QKPH(B0, sA);                                                            \
    SMPH(sA, pA);                                                            \
    QKPH(B1, sB);                                                            \
    PVPH(B0, pA);                                                            \
    SMPH(sB, pB);                                                            \
    PVPH(B1, pB);                                                            \
    if (PF) {                                                                \
      asm volatile("s_waitcnt vmcnt(0)" ::: "memory");                       \
      __builtin_amdgcn_s_barrier();                                          \
    }                                                                        \
  }

  // prologue: first pair resident
  STAGE(0, 0);
  STAGE(1, 1);
  asm volatile("s_waitcnt vmcnt(0)" ::: "memory");
  __builtin_amdgcn_s_barrier();

  for (int it = 0; it < 8; ++it) {
    BODY(0, 1, it * 4, 1);
    BODY(2, 3, it * 4 + 2, it < 7);
  }
#undef BODY
#undef PVPH
#undef SMPH
#undef QKPH
#undef STAGE

  // epilogue: reduce lane-partial l across hi, O /= l, packed short4 stores
  const int bb = bh >> 4, h = bh & 15;
#pragma unroll
  for (int f = 0; f < 2; ++f) {
    float l = l_i[f];
    l += __shfl_xor(l, 16);
    l += __shfl_xor(l, 32);
    float rl = 1.0f / l;
    int q = q0 + f * 16 + lrow;
#pragma unroll
    for (int db = 0; db < 4; ++db) {
      short4 pk;
      pk.x = bfc(accO[f][db][0] * rl);
      pk.y = bfc(accO[f][db][1] * rl);
      pk.z = bfc(accO[f][db][2] * rl);
      pk.w = bfc(accO[f][db][3] * rl);
      *(short4*)(Og + (size_t)(bb * LL + q) * DD + h * 64 + db * 16 + hi * 4) = pk;
    }
  }
}

// ---------------- output GEMM: attn[4096,1024] @ WOt + bO -> f32 ----------
// 64x128 tile -> 512 blocks = 2/CU (was 1/CU at 128x128); XCD swizzle keeps
// one 256KB W-panel per XCD L2-resident.
__global__ __launch_bounds__(256) void out_gemm(const short* __restrict__ Ab,
                                                const short* __restrict__ Wt,
                                                const float* __restrict__ bO,
                                                float* __restrict__ Out) {
  __shared__ __align__(16) short As[64 * 32];
  __shared__ __align__(16) short Bs[128 * 32];

  const int tid = threadIdx.x;
  const int lane = tid & 63;
  const int wid = tid >> 6;
  const int orig = blockIdx.x + 8 * blockIdx.y;   // grid (8, 64)
  const int nid = (orig & 7) * 64 + (orig >> 3);  // bijective: 512 = 8*64
  const int n0 = (nid >> 6) * 128;
  const int m0 = (nid & 63) * 64;

  const int wrow = wid >> 1, wcol = wid & 1;  // wave tile: 32 rows x 64 cols
  const int lrow = lane & 15;
  const int lk8 = (lane >> 4) * 8;
  const int srow = lane >> 2;
  const int scol = (lane & 3) * 8;

  f32x4 z4 = {0.f, 0.f, 0.f, 0.f};
  f32x4 acc[2][4];
#pragma unroll
  for (int i = 0; i < 2; ++i)
#pragma unroll
    for (int j = 0; j < 4; ++j) acc[i][j] = z4;

  for (int kt = 0; kt < DD; kt += 32) {
    // A: 64 rows = 4 chunks of 16; one per wave. B: 128 rows = 8; two per wave.
    gl_lds16(Ab + (size_t)(m0 + wid * 16 + srow) * DD + kt + scol, As + wid * 512);
#pragma unroll
    for (int i = 0; i < 2; ++i) {
      int c = wid * 2 + i;
      gl_lds16(Wt + (size_t)(n0 + c * 16 + srow) * DD + kt + scol, Bs + c * 512);
    }
    __syncthreads();
    b16x8 a[2], b[4];
#pragma unroll
    for (int i = 0; i < 2; ++i)
      a[i] = *(const b16x8*)(As + (wrow * 32 + i * 16 + lrow) * 32 + lk8);
#pragma unroll
    for (int j = 0; j < 4; ++j)
      b[j] = *(const b16x8*)(Bs + (wcol * 64 + j * 16 + lrow) * 32 + lk8);
#pragma unroll
    for (int i = 0; i < 2; ++i)
#pragma unroll
      for (int j = 0; j < 4; ++j)
        acc[i][j] = __builtin_amdgcn_mfma_f32_16x16x32_bf16(a[i], b[j], acc[i][j], 0, 0, 0);
    __syncthreads();
  }

  float bv[4];
#pragma unroll
  for (int j = 0; j < 4; ++j) bv[j] = bO[n0 + wcol * 64 + j * 16 + lrow];

  const int rbase = (lane >> 4) * 4;
#pragma unroll
  for (int i = 0; i < 2; ++i) {
    int gm = m0 + wrow * 32 + i * 16 + rbase;
#pragma unroll
    for (int j = 0; j < 4; ++j) {
      int gn = n0 + wcol * 64 + j * 16 + lrow;
#pragma unroll
      for (int r = 0; r < 4; ++r)
        Out[(size_t)(gm + r) * DD + gn] = acc[i][j][r] + bv[j];
    }
  }
}

extern "C" void kernel_launch(void* const* d_in, const int* in_sizes, int n_in,
                              void* d_out, int out_size, void* d_ws, size_t ws_size,
                              hipStream_t stream) {
  const float* X = (const float*)d_in[0];
  const float* WQ = (const float*)d_in[1];
  const float* bQ = (const float*)d_in[2];
  const float* WK = (const float*)d_in[3];
  const float* bK = (const float*)d_in[4];
  const float* WV = (const float*)d_in[5];
  const float* bV = (const float*)d_in[6];
  const float* WO = (const float*)d_in[7];
  const float* bO = (const float*)d_in[8];
  float* Out = (float*)d_out;

  // workspace layout (shorts): Xb 4M | Wt 4x1M | Q 4M | K 4M | Vt 4M | At 4M
  if (ws_size < (size_t)24 * 1024 * 1024 * 2) return;
  short* ws = (short*)d_ws;
  short* Xb = ws;
  short* Wt = Xb + (size_t)4096 * 1024;
  short* Qb = Wt + (size_t)4 * 1024 * 1024;
  short* Kb = Qb + (size_t)4096 * 1024;
  short* Vtb = Kb + (size_t)4096 * 1024;
  short* At = Vtb + (size_t)4096 * 1024;

  hipLaunchKernelGGL(xcvt, dim3(4096), dim3(256), 0, stream, X, Xb);
  hipLaunchKernelGGL(wtrans, dim3(32, 32, 4), dim3(256), 0, stream, WQ, WK, WV, WO, Wt);
  hipLaunchKernelGGL(qkv_gemm, dim3(24, 32), dim3(256), 0, stream, Xb, Wt, bQ, bK, bV,
                     Qb, Kb, Vtb);
  hipLaunchKernelGGL(attn, dim3(16, 32), dim3(256), 0, stream, Qb, Kb, Vtb, At);
  hipLaunchKernelGGL(out_gemm, dim3(8, 64), dim3(256), 0, stream, At,
                     Wt + (size_t)3 * 1024 * 1024, bO, Out);
}

// Round 14
// 111.466 us; speedup vs baseline: 1.0703x; 1.0031x over previous
//
#include <hip/hip_runtime.h>
#include <stdint.h>

#define BB 2
#define HH 16
#define LL 2048
#define DD 1024

typedef __bf16 b16x8 __attribute__((ext_vector_type(8)));
typedef float f32x4 __attribute__((ext_vector_type(4)));
typedef int i32x4 __attribute__((ext_vector_type(4)));

__device__ __forceinline__ short f2bf(float f) {
  unsigned u = __builtin_bit_cast(unsigned, f);
  return (short)((u + 0x7fffu + ((u >> 16) & 1u)) >> 16);
}

// native bf16 convert
__device__ __forceinline__ short bfc(float f) {
  return __builtin_bit_cast(short, static_cast<__bf16>(f));
}

// packed f32x2 -> bf16x2 (no builtin on gfx950; inline asm)
__device__ __forceinline__ int cvtpk(float lo, float hi) {
  int r;
  asm("v_cvt_pk_bf16_f32 %0, %1, %2" : "=v"(r) : "v"(lo), "v"(hi));
  return r;
}

__device__ __forceinline__ void gl_lds16(const void* gp, void* lp) {
  __builtin_amdgcn_global_load_lds(
      (const __attribute__((address_space(1))) void*)gp,
      (__attribute__((address_space(3))) void*)lp, 16, 0, 0);
}

// ---------------- X f32 -> bf16 ----------------
__global__ __launch_bounds__(256) void xcvt(const float* __restrict__ X,
                                            short* __restrict__ Xb) {
  int i = blockIdx.x * 256 + threadIdx.x;
  float4 v = ((const float4*)X)[i];
  short4 o;
  o.x = f2bf(v.x); o.y = f2bf(v.y); o.z = f2bf(v.z); o.w = f2bf(v.w);
  ((short4*)Xb)[i] = o;
}

// ---------------- W[k][n] f32 -> Wt[n][k] bf16 (4 mats via blockIdx.z) ------
__global__ __launch_bounds__(256) void wtrans(const float* __restrict__ W0,
                                              const float* __restrict__ W1,
                                              const float* __restrict__ W2,
                                              const float* __restrict__ W3,
                                              short* __restrict__ Wt) {
  __shared__ float t[32][33];
  const float* W = blockIdx.z == 0 ? W0 : blockIdx.z == 1 ? W1
                 : blockIdx.z == 2 ? W2 : W3;
  short* dst = Wt + (size_t)blockIdx.z * DD * DD;
  int tx = threadIdx.x & 31, ty0 = threadIdx.x >> 5;
  int nb = blockIdx.x * 32, kb = blockIdx.y * 32;
#pragma unroll
  for (int i = 0; i < 4; ++i)
    t[ty0 + i * 8][tx] = W[(size_t)(kb + ty0 + i * 8) * DD + nb + tx];
  __syncthreads();
#pragma unroll
  for (int i = 0; i < 4; ++i)
    dst[(size_t)(nb + ty0 + i * 8) * DD + kb + tx] = f2bf(t[tx][ty0 + i * 8]);
}

// ---------------- fused QKV GEMM: [4096,1024] @ Wt -> Q,K,Vt ---------------
// XCD-chunked swizzle: 768 = 8 x 96; each XCD owns 3 n-panels (L2-resident).
__global__ __launch_bounds__(256) void qkv_gemm(const short* __restrict__ Xb,
                                                const short* __restrict__ Wall,
                                                const float* __restrict__ bQ,
                                                const float* __restrict__ bK,
                                                const float* __restrict__ bV,
                                                short* __restrict__ Qo,
                                                short* __restrict__ Ko,
                                                short* __restrict__ Vto) {
  __shared__ __align__(16) short As[128 * 32];
  __shared__ __align__(16) short Bs[128 * 32];

  const int tid = threadIdx.x;
  const int lane = tid & 63;
  const int wid = tid >> 6;
  const int orig = blockIdx.x + 24 * blockIdx.y;
  const int nid = (orig & 7) * 96 + (orig >> 3);
  const int m0 = (nid & 31) * 128;
  const int ng = (nid >> 5) * 128;
  const int sel = ng >> 10;
  const int n0 = ng & 1023;
  const short* W = Wall + (size_t)sel * DD * DD;

  const int wrow = wid >> 1, wcol = wid & 1;
  const int lrow = lane & 15;
  const int lk8 = (lane >> 4) * 8;
  const int srow = lane >> 2;
  const int scol = (lane & 3) * 8;

  f32x4 z4 = {0.f, 0.f, 0.f, 0.f};
  f32x4 acc[4][4];
#pragma unroll
  for (int i = 0; i < 4; ++i)
#pragma unroll
    for (int j = 0; j < 4; ++j) acc[i][j] = z4;

  for (int kt = 0; kt < DD; kt += 32) {
#pragma unroll
    for (int i = 0; i < 2; ++i) {
      int c = wid * 2 + i;
      gl_lds16(Xb + (size_t)(m0 + c * 16 + srow) * DD + kt + scol, As + c * 512);
      gl_lds16(W + (size_t)(n0 + c * 16 + srow) * DD + kt + scol, Bs + c * 512);
    }
    __syncthreads();
    b16x8 a[4], b[4];
#pragma unroll
    for (int i = 0; i < 4; ++i)
      a[i] = *(const b16x8*)(As + (wrow * 64 + i * 16 + lrow) * 32 + lk8);
#pragma unroll
    for (int j = 0; j < 4; ++j)
      b[j] = *(const b16x8*)(Bs + (wcol * 64 + j * 16 + lrow) * 32 + lk8);
#pragma unroll
    for (int i = 0; i < 4; ++i)
#pragma unroll
      for (int j = 0; j < 4; ++j)
        acc[i][j] = __builtin_amdgcn_mfma_f32_16x16x32_bf16(a[i], b[j], acc[i][j], 0, 0, 0);
    __syncthreads();
  }

  const float* bias = sel == 0 ? bQ : sel == 1 ? bK : bV;
  float bv[4];
#pragma unroll
  for (int j = 0; j < 4; ++j) bv[j] = bias[n0 + wcol * 64 + j * 16 + lrow];

  const int rbase = (lane >> 4) * 4;
  if (sel == 2) {
    // V: write transposed (B,H,DK,L) with keys PERMUTED within each 64-tile:
    // addr(key)= (kf>>1)*32 + hi*8 + (kf&1)*4 + t  (kf=key>>4, hi=(key>>2)&3,
    // t=key&3), so the attention PV fragment = one contiguous 16B b128 read.
#pragma unroll
    for (int i = 0; i < 4; ++i) {
      int gm = m0 + wrow * 64 + i * 16 + rbase;
      int bb = gm >> 11, lb = gm & 2047;
      int x = lb & 63;
      int kf = x >> 4;
      int lbp = (lb & ~63) | ((kf >> 1) << 5) | (((x >> 2) & 3) << 3) | ((kf & 1) << 2);
#pragma unroll
      for (int j = 0; j < 4; ++j) {
        int gn = n0 + wcol * 64 + j * 16 + lrow;
        int h = gn >> 6, dk = gn & 63;
        short4 pk;
        pk.x = bfc(acc[i][j][0] + bv[j]);
        pk.y = bfc(acc[i][j][1] + bv[j]);
        pk.z = bfc(acc[i][j][2] + bv[j]);
        pk.w = bfc(acc[i][j][3] + bv[j]);
        *(short4*)(Vto + ((size_t)((bb * HH + h) * 64 + dk)) * LL + lbp) = pk;
      }
    }
  } else {
    short* dst = sel == 0 ? Qo : Ko;
    // Q: fold 1/sqrt(64) AND log2(e) so softmax runs in exp2 domain.
    float sc = sel == 0 ? 0.18033688011112042f : 1.0f;
#pragma unroll
    for (int i = 0; i < 4; ++i) {
      int gm = m0 + wrow * 64 + i * 16 + rbase;
#pragma unroll
      for (int j = 0; j < 4; ++j) {
        int gn = n0 + wcol * 64 + j * 16 + lrow;
        int h = gn >> 6, dk = gn & 63;
#pragma unroll
        for (int r = 0; r < 4; ++r) {
          int m = gm + r;
          int bb = m >> 11, lq = m & 2047;
          dst[((size_t)(bb * HH + h) * LL + lq) * 64 + dk] =
              bfc((acc[i][j][r] + bv[j]) * sc);
        }
      }
    }
  }
}

// ---------------- flash attention (swapped-operand, 3-ring) ----------------
// grid (16, 32): 128 q-rows/block, 4 waves x 32 rows, XCD-chunked swizzle.
// 3-buffer LDS ring, 2-tile-ahead gl_lds prefetch, counted vmcnt(4) + raw
// s_barrier (never drain in-loop). V keys pre-permuted -> PV read is a
// conflict-free b128. S^T = mfma(K,Q) keeps P in-register; cvt_pk packing;
// hoisted LDS offsets; lane-partial l with single epilogue shuffle-reduce.
// (ones-MFMA l and v_max3 reverted: r13 fail isolated to that pair.)
__global__ __launch_bounds__(256, 2) void attn(const short* __restrict__ Qg,
                                               const short* __restrict__ Kg,
                                               const short* __restrict__ Vt,
                                               short* __restrict__ Og) {
  __shared__ __align__(16) short Ks[3][64 * 64];  // [key][d], swizzled rows
  __shared__ __align__(16) short Vs[3][64 * 64];  // [d][perm-key], swizzled

  const int tid = threadIdx.x;
  const int lane = tid & 63;
  const int wid = tid >> 6;

  // bijective XCD-chunked swizzle: 512 = 8 x 64 -> 4 bh per XCD (2MB KV/L2)
  const int orig = blockIdx.x + 16 * blockIdx.y;
  const int nid = (orig & 7) * 64 + (orig >> 3);
  const int bh = nid >> 4;
  const int q0 = (nid & 15) * 128 + wid * 32;

  const short* Qb = Qg + (size_t)bh * LL * 64;
  const short* Kb = Kg + (size_t)bh * LL * 64;
  const short* Vb = Vt + (size_t)bh * 64 * LL;

  const int lrow = lane & 15;
  const int hi = lane >> 4;     // 0..3
  const int hi8 = hi * 8;       // shorts
  const int hi16b = hi * 16;    // bytes
  const int r8 = lane >> 3;     // staging row within 8-row chunk
  const int c8 = lane & 7;
  const int swz8 = (c8 ^ r8) * 8;  // pre-swizzled global source offset (elems)

  // Q fragment: B-operand of swapped QK (col=q=lrow, k=hi*8+j)
  b16x8 qf[2][2];
#pragma unroll
  for (int f = 0; f < 2; ++f)
#pragma unroll
    for (int ks = 0; ks < 2; ++ks)
      qf[f][ks] = *(const b16x8*)(Qb + (size_t)(q0 + f * 16 + lrow) * 64 + ks * 32 + hi8);

  f32x4 z4 = {0.f, 0.f, 0.f, 0.f};
  f32x4 accO[2][4];   // accO[f][db]: O^T[d=db*16+hi*4+r][q=f*16+lrow]
  float m_i[2], l_i[2];  // l_i LANE-PARTIAL across hi (reduced at epilogue)
#pragma unroll
  for (int f = 0; f < 2; ++f) {
#pragma unroll
    for (int d = 0; d < 4; ++d) accO[f][d] = z4;
    m_i[f] = -1e30f; l_i[f] = 0.f;
  }

  // hoisted LDS read byte-offsets (identical table for K and V reads)
  int offs[4][2];
#pragma unroll
  for (int a = 0; a < 4; ++a) {
    int row = a * 16 + lrow;
    int sw = (row & 7) << 4;
#pragma unroll
    for (int ks = 0; ks < 2; ++ks)
      offs[a][ks] = row * 128 + ((ks * 64 + hi16b) ^ sw);
  }

  // stage tile kt_ into ring buffer buf_ (4 gl_lds per wave: 2 K + 2 V)
  auto stage = [&](int kt_, int buf_) {
#pragma unroll
    for (int i = 0; i < 2; ++i) {
      int c = wid * 2 + i;
      gl_lds16(Kb + (size_t)(kt_ * 64 + c * 8 + r8) * 64 + swz8, &Ks[buf_][c * 512]);
      gl_lds16(Vb + (size_t)(c * 8 + r8) * LL + kt_ * 64 + swz8, &Vs[buf_][c * 512]);
    }
  };

  // prologue: 2 tiles in flight
  stage(0, 0);
  stage(1, 1);
  asm volatile("s_waitcnt vmcnt(4)" ::: "memory");  // tile0 resident
  __builtin_amdgcn_s_barrier();

  int cur = 0;
  for (int kt = 0; kt < LL / 64; ++kt) {
    // prefetch tile kt+2 into ring slot cur+2 (stays in flight past barrier)
    if (kt + 2 < LL / 64) {
      int pb = cur + 2;
      if (pb >= 3) pb -= 3;
      stage(kt + 2, pb);
    }

    const char* ksb = (const char*)&Ks[cur][0];
    const char* vsb = (const char*)&Vs[cur][0];

    // S^T = mfma(K, Q): sacc[f][kf][r] = S[key=kf*16+hi*4+r][q=f*16+lrow]
    f32x4 sacc[2][4];
#pragma unroll
    for (int f = 0; f < 2; ++f)
#pragma unroll
      for (int kf = 0; kf < 4; ++kf) sacc[f][kf] = z4;

    __builtin_amdgcn_s_setprio(1);
#pragma unroll
    for (int kf = 0; kf < 4; ++kf) {
#pragma unroll
      for (int ks = 0; ks < 2; ++ks) {
        b16x8 kfr = *(const b16x8*)(ksb + offs[kf][ks]);
#pragma unroll
        for (int f = 0; f < 2; ++f)
          sacc[f][kf] =
              __builtin_amdgcn_mfma_f32_16x16x32_bf16(kfr, qf[f][ks], sacc[f][kf], 0, 0, 0);
      }
    }
    __builtin_amdgcn_s_setprio(0);

    // ---- defer-max online softmax (keys lane-local) ----
    float lm[2];
#pragma unroll
    for (int f = 0; f < 2; ++f) {
      float mx = fmaxf(fmaxf(sacc[f][0][0], sacc[f][0][1]),
                       fmaxf(sacc[f][0][2], sacc[f][0][3]));
#pragma unroll
      for (int kf = 1; kf < 4; ++kf)
        mx = fmaxf(mx, fmaxf(fmaxf(sacc[f][kf][0], sacc[f][kf][1]),
                             fmaxf(sacc[f][kf][2], sacc[f][kf][3])));
      lm[f] = mx;
    }
    float w = fmaxf(lm[0] - m_i[0], lm[1] - m_i[1]);

    if (!__all(w <= 8.0f)) {
      // rare path: reduce max across the 4 hi-lanes sharing each q, rescale
#pragma unroll
      for (int f = 0; f < 2; ++f) {
        float mx = lm[f];
        mx = fmaxf(mx, __shfl_xor(mx, 16));
        mx = fmaxf(mx, __shfl_xor(mx, 32));
        float mnew = fmaxf(m_i[f], mx);
        float corr = __builtin_amdgcn_exp2f(m_i[f] - mnew);
        l_i[f] *= corr;
        m_i[f] = mnew;
#pragma unroll
        for (int d = 0; d < 4; ++d) accO[f][d] *= corr;
      }
    }

    // P = exp2(S - m) packed via v_cvt_pk_bf16_f32 into the PV B-fragment.
    // PV k-order: tau(ks, hi*8+j) = (2ks + (j>>2))*16 + hi*4 + (j&3)
    b16x8 pfr[2][2];
#pragma unroll
    for (int f = 0; f < 2; ++f) {
      float ps = 0.f;
#pragma unroll
      for (int c = 0; c < 2; ++c) {
        float e0 = __builtin_amdgcn_exp2f(sacc[f][2 * c][0] - m_i[f]);
        float e1 = __builtin_amdgcn_exp2f(sacc[f][2 * c][1] - m_i[f]);
        float e2 = __builtin_amdgcn_exp2f(sacc[f][2 * c][2] - m_i[f]);
        float e3 = __builtin_amdgcn_exp2f(sacc[f][2 * c][3] - m_i[f]);
        float e4 = __builtin_amdgcn_exp2f(sacc[f][2 * c + 1][0] - m_i[f]);
        float e5 = __builtin_amdgcn_exp2f(sacc[f][2 * c + 1][1] - m_i[f]);
        float e6 = __builtin_amdgcn_exp2f(sacc[f][2 * c + 1][2] - m_i[f]);
        float e7 = __builtin_amdgcn_exp2f(sacc[f][2 * c + 1][3] - m_i[f]);
        ps += ((e0 + e1) + (e2 + e3)) + ((e4 + e5) + (e6 + e7));
        i32x4 pt;
        pt[0] = cvtpk(e0, e1);
        pt[1] = cvtpk(e2, e3);
        pt[2] = cvtpk(e4, e5);
        pt[3] = cvtpk(e6, e7);
        pfr[f][c] = __builtin_bit_cast(b16x8, pt);
      }
      l_i[f] += ps;
    }

    // V fragment (A-operand): permuted key layout -> one conflict-free b128
    b16x8 vfr[4][2];
#pragma unroll
    for (int db = 0; db < 4; ++db) {
#pragma unroll
      for (int ks = 0; ks < 2; ++ks)
        vfr[db][ks] = *(const b16x8*)(vsb + offs[db][ks]);
    }

    // O^T += mfma(V, P)
    __builtin_amdgcn_s_setprio(1);
#pragma unroll
    for (int f = 0; f < 2; ++f) {
#pragma unroll
      for (int db = 0; db < 4; ++db) {
        accO[f][db] = __builtin_amdgcn_mfma_f32_16x16x32_bf16(vfr[db][0], pfr[f][0],
                                                              accO[f][db], 0, 0, 0);
        accO[f][db] = __builtin_amdgcn_mfma_f32_16x16x32_bf16(vfr[db][1], pfr[f][1],
                                                              accO[f][db], 0, 0, 0);
      }
    }
    __builtin_amdgcn_s_setprio(0);

    // retire tile kt+1's 4 loads; keep kt+2's in flight across the barrier
    if (kt + 2 < LL / 64) {
      asm volatile("s_waitcnt vmcnt(4)" ::: "memory");
      __builtin_amdgcn_s_barrier();
    } else if (kt + 1 < LL / 64) {
      asm volatile("s_waitcnt vmcnt(0)" ::: "memory");
      __builtin_amdgcn_s_barrier();
    }
    cur = cur + 1 >= 3 ? 0 : cur + 1;
  }

  // epilogue: reduce lane-partial l across hi, O /= l, packed short4 stores
  const int bb = bh >> 4, h = bh & 15;
#pragma unroll
  for (int f = 0; f < 2; ++f) {
    float l = l_i[f];
    l += __shfl_xor(l, 16);
    l += __shfl_xor(l, 32);
    float rl = 1.0f / l;
    int q = q0 + f * 16 + lrow;
#pragma unroll
    for (int db = 0; db < 4; ++db) {
      short4 pk;
      pk.x = bfc(accO[f][db][0] * rl);
      pk.y = bfc(accO[f][db][1] * rl);
      pk.z = bfc(accO[f][db][2] * rl);
      pk.w = bfc(accO[f][db][3] * rl);
      *(short4*)(Og + (size_t)(bb * LL + q) * DD + h * 64 + db * 16 + hi * 4) = pk;
    }
  }
}

// ---------------- output GEMM: attn[4096,1024] @ WOt + bO -> f32 ----------
// 64x128 tile -> 512 blocks = 2/CU; XCD swizzle keeps one W-panel per XCD
// L2-resident.
__global__ __launch_bounds__(256) void out_gemm(const short* __restrict__ Ab,
                                                const short* __restrict__ Wt,
                                                const float* __restrict__ bO,
                                                float* __restrict__ Out) {
  __shared__ __align__(16) short As[64 * 32];
  __shared__ __align__(16) short Bs[128 * 32];

  const int tid = threadIdx.x;
  const int lane = tid & 63;
  const int wid = tid >> 6;
  const int orig = blockIdx.x + 8 * blockIdx.y;   // grid (8, 64)
  const int nid = (orig & 7) * 64 + (orig >> 3);  // bijective: 512 = 8*64
  const int n0 = (nid >> 6) * 128;
  const int m0 = (nid & 63) * 64;

  const int wrow = wid >> 1, wcol = wid & 1;  // wave tile: 32 rows x 64 cols
  const int lrow = lane & 15;
  const int lk8 = (lane >> 4) * 8;
  const int srow = lane >> 2;
  const int scol = (lane & 3) * 8;

  f32x4 z4 = {0.f, 0.f, 0.f, 0.f};
  f32x4 acc[2][4];
#pragma unroll
  for (int i = 0; i < 2; ++i)
#pragma unroll
    for (int j = 0; j < 4; ++j) acc[i][j] = z4;

  for (int kt = 0; kt < DD; kt += 32) {
    // A: 64 rows = 4 chunks of 16; one per wave. B: 128 rows = 8; two per wave.
    gl_lds16(Ab + (size_t)(m0 + wid * 16 + srow) * DD + kt + scol, As + wid * 512);
#pragma unroll
    for (int i = 0; i < 2; ++i) {
      int c = wid * 2 + i;
      gl_lds16(Wt + (size_t)(n0 + c * 16 + srow) * DD + kt + scol, Bs + c * 512);
    }
    __syncthreads();
    b16x8 a[2], b[4];
#pragma unroll
    for (int i = 0; i < 2; ++i)
      a[i] = *(const b16x8*)(As + (wrow * 32 + i * 16 + lrow) * 32 + lk8);
#pragma unroll
    for (int j = 0; j < 4; ++j)
      b[j] = *(const b16x8*)(Bs + (wcol * 64 + j * 16 + lrow) * 32 + lk8);
#pragma unroll
    for (int i = 0; i < 2; ++i)
#pragma unroll
      for (int j = 0; j < 4; ++j)
        acc[i][j] = __builtin_amdgcn_mfma_f32_16x16x32_bf16(a[i], b[j], acc[i][j], 0, 0, 0);
    __syncthreads();
  }

  float bv[4];
#pragma unroll
  for (int j = 0; j < 4; ++j) bv[j] = bO[n0 + wcol * 64 + j * 16 + lrow];

  const int rbase = (lane >> 4) * 4;
#pragma unroll
  for (int i = 0; i < 2; ++i) {
    int gm = m0 + wrow * 32 + i * 16 + rbase;
#pragma unroll
    for (int j = 0; j < 4; ++j) {
      int gn = n0 + wcol * 64 + j * 16 + lrow;
#pragma unroll
      for (int r = 0; r < 4; ++r)
        Out[(size_t)(gm + r) * DD + gn] = acc[i][j][r] + bv[j];
    }
  }
}

extern "C" void kernel_launch(void* const* d_in, const int* in_sizes, int n_in,
                              void* d_out, int out_size, void* d_ws, size_t ws_size,
                              hipStream_t stream) {
  const float* X = (const float*)d_in[0];
  const float* WQ = (const float*)d_in[1];
  const float* bQ = (const float*)d_in[2];
  const float* WK = (const float*)d_in[3];
  const float* bK = (const float*)d_in[4];
  const float* WV = (const float*)d_in[5];
  const float* bV = (const float*)d_in[6];
  const float* WO = (const float*)d_in[7];
  const float* bO = (const float*)d_in[8];
  float* Out = (float*)d_out;

  // workspace layout (shorts): Xb 4M | Wt 4x1M | Q 4M | K 4M | Vt 4M | At 4M
  if (ws_size < (size_t)24 * 1024 * 1024 * 2) return;
  short* ws = (short*)d_ws;
  short* Xb = ws;
  short* Wt = Xb + (size_t)4096 * 1024;
  short* Qb = Wt + (size_t)4 * 1024 * 1024;
  short* Kb = Qb + (size_t)4096 * 1024;
  short* Vtb = Kb + (size_t)4096 * 1024;
  short* At = Vtb + (size_t)4096 * 1024;

  hipLaunchKernelGGL(xcvt, dim3(4096), dim3(256), 0, stream, X, Xb);
  hipLaunchKernelGGL(wtrans, dim3(32, 32, 4), dim3(256), 0, stream, WQ, WK, WV, WO, Wt);
  hipLaunchKernelGGL(qkv_gemm, dim3(24, 32), dim3(256), 0, stream, Xb, Wt, bQ, bK, bV,
                     Qb, Kb, Vtb);
  hipLaunchKernelGGL(attn, dim3(16, 32), dim3(256), 0, stream, Qb, Kb, Vtb, At);
  hipLaunchKernelGGL(out_gemm, dim3(8, 64), dim3(256), 0, stream, At,
                     Wt + (size_t)3 * 1024 * 1024, bO, Out);
}